// Round 10
// baseline (551.879 us; speedup 1.0000x reference)
//
#include <hip/hip_runtime.h>

#define B_   20
#define T_   20
#define RN   20
#define D_   4096
#define O_   16
#define E_   512
#define H_   8
#define DH   64
#define TM_  1900
#define MREG 8192         // region rows padded to 32*256
#define NW   1536         // Wk|Wv|W1 output channels
#define NSIM 2048         // TM padded to 8*256
#define MSIM 512          // B*T padded to 2*256
#define CAP  256

using f32x4  = __attribute__((ext_vector_type(4))) float;
using bf16x8 = __attribute__((ext_vector_type(8))) __bf16;

__device__ __forceinline__ unsigned short f2bf(float f){
  unsigned u = __float_as_uint(f);
  u += 0x7fffu + ((u >> 16) & 1u);
  return (unsigned short)(u >> 16);
}

__device__ __forceinline__ void st_bf4(unsigned short* dst, float4 v){
  ushort4 o = make_ushort4(f2bf(v.x), f2bf(v.y), f2bf(v.z), f2bf(v.w));
  *(ushort4*)dst = o;
}

__device__ __forceinline__ float bsum256(float v, float* sh){
  int t = threadIdx.x;
  for (int o = 32; o; o >>= 1) v += __shfl_down(v, o, 64);
  __syncthreads();
  if ((t & 63) == 0) sh[t >> 6] = v;
  __syncthreads();
  return sh[0] + sh[1] + sh[2] + sh[3];
}

__device__ __forceinline__ float bmax256(float v, float* sh){
  int t = threadIdx.x;
  for (int o = 32; o; o >>= 1) v = fmaxf(v, __shfl_down(v, o, 64));
  __syncthreads();
  if ((t & 63) == 0) sh[t >> 6] = v;
  __syncthreads();
  return fmaxf(fmaxf(sh[0], sh[1]), fmaxf(sh[2], sh[3]));
}

__device__ __forceinline__ void gld16(const void* g, void* l){
  __builtin_amdgcn_global_load_lds(
      (const __attribute__((address_space(1))) unsigned int*)g,
      (__attribute__((address_space(3))) unsigned int*)l, 16, 0, 0);
}

// ================= fused preprocessing =================
// [0,2048):   temporal-mem max-pool -> umax/msum/gbf (+pads)
// [2048,2560): region pass -> A_kv (row=bt*20+r), rmaxr, rmsum, ubf (+pads)
// [2560,8704): weight transpose+convert -> Wall
// [8704,9024): q = (onehot@entity_W + b) @ Wq
__global__ __launch_bounds__(256) void k_pre(
    const float* __restrict__ F, const float* __restrict__ TMm,
    const float* __restrict__ Wk, const float* __restrict__ Wv, const float* __restrict__ W1,
    unsigned short* __restrict__ Wall,
    unsigned short* __restrict__ A, float* __restrict__ rmaxr, float* __restrict__ rmsum,
    unsigned short* __restrict__ ubf,
    float* __restrict__ umax, float* __restrict__ msum, unsigned short* __restrict__ gbf,
    const int* __restrict__ labels, const float* __restrict__ entW, const float* __restrict__ entB,
    const float* __restrict__ Wq, float* __restrict__ q){
  __shared__ char smem[4352];
  int bid = blockIdx.x, t = threadIdx.x;
  if (bid < 2048){
    int m = bid;
    if (m >= TM_){   // zero gbf pad rows (sim/G B,A pads)
      int4 zz = make_int4(0,0,0,0);
      int4* r2 = (int4*)(gbf + (size_t)m*D_);
      r2[t] = zz; r2[t + 256] = zz;
      return;
    }
    float* sh = (float*)smem;
    const float* base = TMm + (size_t)m*T_*D_;
    float4 mx[4];
#pragma unroll
    for (int i = 0; i < 4; ++i) mx[i] = make_float4(-1e30f,-1e30f,-1e30f,-1e30f);
    float4 va[2][4];
#pragma unroll
    for (int i = 0; i < 4; ++i) va[0][i] = *(const float4*)(base + i*1024 + t*4);
#pragma unroll
    for (int f = 0; f < T_; ++f){
      int c = f & 1;
      if (f + 1 < T_){   // prefetch next frame while reducing current
#pragma unroll
        for (int i = 0; i < 4; ++i)
          va[c^1][i] = *(const float4*)(base + (size_t)(f+1)*D_ + i*1024 + t*4);
      }
#pragma unroll
      for (int i = 0; i < 4; ++i){
        mx[i].x = fmaxf(mx[i].x, va[c][i].x); mx[i].y = fmaxf(mx[i].y, va[c][i].y);
        mx[i].z = fmaxf(mx[i].z, va[c][i].z); mx[i].w = fmaxf(mx[i].w, va[c][i].w);
      }
    }
    float s = 0.f;
#pragma unroll
    for (int i = 0; i < 4; ++i){
      *(float4*)(umax + (size_t)m*D_ + i*1024 + t*4) = mx[i];
      st_bf4(gbf + (size_t)m*D_ + i*1024 + t*4, mx[i]);   // sim-B and G-A operand
      s += mx[i].x*mx[i].x + mx[i].y*mx[i].y + mx[i].z*mx[i].z + mx[i].w*mx[i].w;
    }
    s = bsum256(s, sh);
    if (t == 0) msum[m] = s;
  } else if (bid < 2560){
    int bt = bid - 2048;
    if (bt >= 400){  // zero ubf pad row + two A_kv pad rows
      int4 zz = make_int4(0,0,0,0);
      int4* r1 = (int4*)(ubf + (size_t)bt*D_);
      r1[t] = zz; r1[t + 256] = zz;
      int base = 8000 + (bt - 400)*2;
#pragma unroll
      for (int k = 0; k < 2; ++k){
        if (base + k < MREG){
          int4* r2 = (int4*)(A + (size_t)(base + k)*D_);
          r2[t] = zz; r2[t + 256] = zz;
        }
      }
      return;
    }
    float* sh = (float*)smem;
    const float* fb = F + (size_t)bt*RN*D_;
    unsigned short* ab = A + (size_t)bt*RN*D_;
    float4 mx[4];
#pragma unroll
    for (int i = 0; i < 4; ++i) mx[i] = make_float4(-1e30f,-1e30f,-1e30f,-1e30f);
    float4 vn[4];
#pragma unroll
    for (int i = 0; i < 4; ++i) vn[i] = *(const float4*)(fb + i*1024 + t*4);
    for (int r = 0; r < RN; ++r){
      float4 v[4];
      float s = 0.f;
#pragma unroll
      for (int i = 0; i < 4; ++i){
        v[i] = vn[i];
        s += v[i].x*v[i].x + v[i].y*v[i].y + v[i].z*v[i].z + v[i].w*v[i].w;
      }
      if (r + 1 < RN){   // prefetch next row before the barrier-reduce
#pragma unroll
        for (int i = 0; i < 4; ++i)
          vn[i] = *(const float4*)(fb + (size_t)(r+1)*D_ + i*1024 + t*4);
      }
      s = bsum256(s, sh);
      float ri = 1.f / fmaxf(sqrtf(s), 1e-12f);
#pragma unroll
      for (int i = 0; i < 4; ++i){
        v[i].x *= ri; v[i].y *= ri; v[i].z *= ri; v[i].w *= ri;
        st_bf4(ab + (size_t)r*D_ + i*1024 + t*4, v[i]);
        mx[i].x = fmaxf(mx[i].x, v[i].x); mx[i].y = fmaxf(mx[i].y, v[i].y);
        mx[i].z = fmaxf(mx[i].z, v[i].z); mx[i].w = fmaxf(mx[i].w, v[i].w);
      }
    }
    float s2 = 0.f;
#pragma unroll
    for (int i = 0; i < 4; ++i){
      *(float4*)(rmaxr + (size_t)bt*D_ + i*1024 + t*4) = mx[i];
      s2 += mx[i].x*mx[i].x + mx[i].y*mx[i].y + mx[i].z*mx[i].z + mx[i].w*mx[i].w;
    }
    s2 = bsum256(s2, sh);
    if (t == 0) rmsum[bt] = s2;
    float inv = 1.f / fmaxf(sqrtf(s2), 1e-12f);
#pragma unroll
    for (int i = 0; i < 4; ++i){
      float4 u = mx[i];
      u.x *= inv; u.y *= inv; u.z *= inv; u.w *= inv;
      st_bf4(ubf + (size_t)bt*D_ + i*1024 + t*4, u);
    }
  } else if (bid < 8704){
    int wti = bid - 2560;
    float* tile = (float*)smem;          // [32][33]
    int kb = (wti & 127) * 32, nb = (wti >> 7) * 32;
    const float* src; int nc0;
    if (nb < 512)      { src = Wk; nc0 = nb; }
    else if (nb < 1024){ src = Wv; nc0 = nb - 512; }
    else               { src = W1; nc0 = nb - 1024; }
    int tx = t & 31, ty = t >> 5;
#pragma unroll
    for (int j = 0; j < 4; ++j){
      int k = kb + ty + j*8;
      tile[(ty + j*8)*33 + tx] = src[(size_t)k*E_ + nc0 + tx];
    }
    __syncthreads();
#pragma unroll
    for (int j = 0; j < 4; ++j){
      int n = nb + ty + j*8;
      int k = kb + tx;
      Wall[(size_t)n*D_ + k] = f2bf(tile[tx*33 + ty + j*8]);
    }
  } else {
    int bo = bid - 8704;
    float* qe = (float*)smem;
    int lab = labels[bo];
    float sel = (lab != 0) ? 1.f : 0.f;
    qe[t]       = sel * entW[(size_t)lab*E_ + t]       + entB[t];
    qe[t + 256] = sel * entW[(size_t)lab*E_ + t + 256] + entB[t + 256];
    __syncthreads();
    float a0 = 0.f, a1 = 0.f;
    for (int ep = 0; ep < E_; ++ep){
      float r = qe[ep];
      a0 += r * Wq[(size_t)ep*E_ + t];
      a1 += r * Wq[(size_t)ep*E_ + t + 256];
    }
    q[(size_t)bo*E_ + t] = a0;
    q[(size_t)bo*E_ + t + 256] = a1;
  }
}

// ---------- combined 256x128 bf16 GEMM dispatch: mega | G | sim ----------
// 512 blocks = 2/CU (48KB LDS, <=128 VGPR via launch_bounds): inter-block wave
// overlap absorbs the per-tile barrier drain (m114). BK=32, 2 buffers, 2-phase
// (stage next tile, compute, one barrier). 8 waves as 4M x 2N, per-wave 64x64
// output (64 acc VGPR). K order identical to prior rounds -> bit-identical C.
// [0,384) mega 32x12, [384,480) G 8x12, [480,512) sim 2x16.
__global__ __launch_bounds__(512, 4) void k_gemm3(
    const unsigned short* __restrict__ Akv, const unsigned short* __restrict__ Wall,
    const unsigned short* __restrict__ ubf, const unsigned short* __restrict__ gbf,
    float* __restrict__ C2, float* __restrict__ simc, float* __restrict__ Gc){
  __shared__ char lds[98304];    // buf c at c*24576: A[256][32] @ +0, B[128][32] @ +16384
  int bid = blockIdx.x;
  bid = (bid & 7)*64 + (bid >> 3);   // XCD swizzle (512 % 8 == 0: bijective)
  const unsigned short *A, *Bw; float* C; int nNt, ldc, mt, nt;
  if (bid < 384){       A = Akv; Bw = Wall;  C = C2;   nNt = 12; ldc = NW;   mt = bid/12;  nt = bid%12; }
  else if (bid < 480){  int s = bid - 384;
                        A = gbf; Bw = Wall;  C = Gc;   nNt = 12; ldc = NW;   mt = s/12;    nt = s%12; }
  else {                int s = bid - 480;
                        A = ubf; Bw = gbf;   C = simc; nNt = 16; ldc = NSIM; mt = s/16;    nt = s%16; }
  int tid = threadIdx.x, wid = tid >> 6, l = tid & 63;
  int wr = (wid >> 1) * 64;      // 4 waves in M (256 rows)
  int wc = (wid & 1) * 64;       // 2 waves in N (128 cols)
  int fr = l & 15, fq = l >> 4;
  const char* Ab = (const char*)A + (size_t)mt*256*(size_t)(D_*2);
  const char* Bb = (const char*)Bw + (size_t)nt*128*(size_t)(D_*2);
  f32x4 acc[4][4];
#pragma unroll
  for (int m = 0; m < 4; ++m)
#pragma unroll
    for (int n = 0; n < 4; ++n) acc[m][n] = (f32x4){0.f,0.f,0.f,0.f};

  // stage one BK=32 tile (A 256x64B + B 128x64B = 3 gld16/thread); src
  // pre-swizzled with the matching XOR (G21)
  auto stage = [&](char* dstbuf, int ktoff){
#pragma unroll
    for (int j = 0; j < 2; ++j){           // A: 1024 16B-chunks
      int idx = j*512 + tid;
      int row = idx >> 2, u = idx & 3;
      int ul = u ^ (row & 3);
      gld16(Ab + (size_t)row*(size_t)(D_*2) + ktoff + ul*16, dstbuf + idx*16);
    }
    {                                       // B: 512 16B-chunks
      int idx = tid;
      int row = idx >> 2, u = idx & 3;
      int ul = u ^ (row & 3);
      gld16(Bb + (size_t)row*(size_t)(D_*2) + ktoff + ul*16, dstbuf + 16384 + idx*16);
    }
  };

  stage(lds, 0);                 // prologue: K-tile 0 into buf 0
  __syncthreads();

  for (int kt = 0; kt < D_/32; ++kt){
    char* curb = lds + (kt & 1)*24576;
    if (kt < D_/32 - 1)
      stage(lds + ((kt & 1)^1)*24576, (kt + 1)*64);   // issue next tile early
    bf16x8 av[4], bv[4];
#pragma unroll
    for (int m = 0; m < 4; ++m){
      int row = wr + m*16 + fr;
      int u = fq ^ (row & 3);
      av[m] = *(const bf16x8*)(curb + row*64 + u*16);
    }
#pragma unroll
    for (int n = 0; n < 4; ++n){
      int row = wc + n*16 + fr;
      int u = fq ^ (row & 3);
      bv[n] = *(const bf16x8*)(curb + 16384 + row*64 + u*16);
    }
    __builtin_amdgcn_s_setprio(1);
#pragma unroll
    for (int m = 0; m < 4; ++m)
#pragma unroll
      for (int n = 0; n < 4; ++n)
        acc[m][n] = __builtin_amdgcn_mfma_f32_16x16x32_bf16(av[m], bv[n], acc[m][n], 0, 0, 0);
    __builtin_amdgcn_s_setprio(0);
    __syncthreads();             // drains vmcnt(0); partner block covers the stall
  }
  size_t crow0 = (size_t)mt*256 + wr, ccol0 = (size_t)nt*128 + wc;
#pragma unroll
  for (int m = 0; m < 4; ++m)
#pragma unroll
    for (int n = 0; n < 4; ++n){
      size_t r0 = crow0 + m*16 + fq*4, c0 = ccol0 + n*16 + fr;
#pragma unroll
      for (int j = 0; j < 4; ++j)
        C[(r0 + j)*(size_t)ldc + c0] = acc[m][n][j];
    }
}

// ---------- prune + fp32 rescore + gather precomputed G row into C2 mem rows ----------
__global__ __launch_bounds__(256) void k_pick(const float* __restrict__ simc,
                                              const float* __restrict__ rmaxr, const float* __restrict__ rmsum,
                                              const float* __restrict__ umax, const float* __restrict__ msum,
                                              const float* __restrict__ Gc, float* __restrict__ C2){
  int bt = blockIdx.x, t = threadIdx.x;
  __shared__ float srow[1920];
  __shared__ float sh[4];
  __shared__ int cnt;
  __shared__ int cl[CAP];
  for (int m = t; m < TM_; m += 256)
    srow[m] = simc[(size_t)bt*NSIM + m] * (1.f / fmaxf(sqrtf(msum[m]), 1e-12f));
  if (t == 0) cnt = 0;
  __syncthreads();
  float mx = -1e30f;
  for (int m = t; m < TM_; m += 256) mx = fmaxf(mx, srow[m]);
  mx = bmax256(mx, sh);
  float thr = mx - 2.5e-4f;
  for (int m = t; m < TM_; m += 256){
    if (srow[m] >= thr){
      int p = atomicAdd(&cnt, 1);
      if (p < CAP) cl[p] = m;
    }
  }
  __syncthreads();
  int cn = cnt < CAP ? cnt : CAP;
  float rinvv = 1.f / fmaxf(sqrtf(rmsum[bt]), 1e-12f);
  const float* a = rmaxr + (size_t)bt*D_;
  float best = -1e30f; int bestm = 0x7fffffff;
  for (int ci = 0; ci < cn; ++ci){
    int m = cl[ci];
    const float* wrow = umax + (size_t)m*D_;
    float p = 0.f;
    for (int i = t*4; i < D_; i += 1024){
      float4 av = *(const float4*)(a + i);
      float4 wv = *(const float4*)(wrow + i);
      p += av.x*wv.x + av.y*wv.y + av.z*wv.z + av.w*wv.w;
    }
    p = bsum256(p, sh);
    float sim = p * rinvv * (1.f / fmaxf(sqrtf(msum[m]), 1e-12f));
    if (sim > best || (sim == best && m < bestm)){ best = sim; bestm = m; }
  }
  // gather precomputed mem-row outputs: C2 row (MREG + bt) = Gc[bestm]
  const float4* src = (const float4*)(Gc + (size_t)bestm*NW);
  float4* dst = (float4*)(C2 + (size_t)(MREG + bt)*NW);
  if (t < 128){ dst[t] = src[t]; dst[t + 128] = src[t + 128]; dst[t + 256] = src[t + 256]; }
}

// ================= fused post-GEMM =================
// [0,160): attention per (b,h) ; [160,560): hi/lo per (b,t) ; [560,2560): z-MLP
// C2 row map: region (b,n<400) -> b*400+n ; mem (b,tt) -> MREG + b*20 + tt
__global__ __launch_bounds__(256) void k_post(const float* __restrict__ q, const float* __restrict__ c2,
                                              float* __restrict__ fpre, int* __restrict__ hi,
                                              int* __restrict__ lo, const float* __restrict__ b1,
                                              const float* __restrict__ W2, const float* __restrict__ b2,
                                              float* __restrict__ z){
  __shared__ char smem[58368];
  int bid = blockIdx.x, t = threadIdx.x;
  if (bid < 160){
    int b = bid >> 3, h = bid & 7;
    int w = t >> 6, l = t & 63;
    float* qhp = (float*)smem;               // [16][65]
    float* kb  = (float*)(smem + 4160);      // [105][65]
    float* sc  = (float*)(smem + 31460);     // [16][420]
    for (int i = t; i < O_*DH; i += 256){
      int o = i >> 6, d = i & 63;
      qhp[o*65 + d] = q[((size_t)(b*O_ + o))*E_ + h*DH + d] * 0.125f;
    }
    __syncthreads();
    for (int c = 0; c < 4; ++c){
      for (int i = t; i < 105*DH; i += 256){
        int j = i >> 6, d = i & 63;
        int n = c*105 + j;
        size_t row = n < 400 ? (size_t)b*400 + n : (size_t)MREG + b*20 + (n - 400);
        kb[j*65 + d] = c2[row*NW + h*DH + d];
      }
      __syncthreads();
      for (int i = t; i < O_*105; i += 256){
        int o = i / 105, j = i % 105;
        float acc = 0.f;
        for (int d = 0; d < DH; ++d) acc += qhp[o*65 + d] * kb[j*65 + d];
        sc[o*420 + c*105 + j] = acc;
      }
      __syncthreads();
    }
    for (int oi = 0; oi < 4; ++oi){
      int o = w + oi*4;
      float mxv = -1e30f;
      for (int n = l; n < 420; n += 64) mxv = fmaxf(mxv, sc[o*420 + n]);
      for (int of = 32; of; of >>= 1) mxv = fmaxf(mxv, __shfl_xor(mxv, of, 64));
      float sum = 0.f;
      for (int n = l; n < 420; n += 64){ float e = expf(sc[o*420 + n] - mxv); sc[o*420 + n] = e; sum += e; }
      for (int of = 32; of; of >>= 1) sum += __shfl_xor(sum, of, 64);
      float inv = 1.f / sum;
      for (int n = l; n < 420; n += 64) sc[o*420 + n] *= inv;
    }
    __syncthreads();
    float acc[4] = {0.f, 0.f, 0.f, 0.f};
    for (int c = 0; c < 4; ++c){
      for (int i = t; i < 105*DH; i += 256){
        int j = i >> 6, d = i & 63;
        int n = c*105 + j;
        size_t row = n < 400 ? (size_t)b*400 + n : (size_t)MREG + b*20 + (n - 400);
        kb[j*65 + d] = c2[row*NW + E_ + h*DH + d];
      }
      __syncthreads();
#pragma unroll
      for (int og = 0; og < 4; ++og){
        int o = og*4 + w;
        float a = 0.f;
        for (int j = 0; j < 105; ++j) a += sc[o*420 + c*105 + j] * kb[j*65 + l];
        acc[og] += a;
      }
      __syncthreads();
    }
#pragma unroll
    for (int og = 0; og < 4; ++og){
      int o = og*4 + w;
      fpre[((size_t)(b*O_ + o))*E_ + h*DH + l] = acc[og];
    }
  } else if (bid < 560){
    int bt = bid - 160;
    int b = bt / T_, tt = bt % T_;
    float* kl = (float*)smem;                // [20][513]
    float* qr = (float*)(smem + 41040);      // [16][20]
    for (int i = t; i < RN*E_; i += 256){
      int r = i >> 9, e = i & 511;
      kl[r*513 + e] = c2[((size_t)b*400 + tt*RN + r)*NW + e];
    }
    __syncthreads();
#pragma unroll
    for (int pp = 0; pp < 2; ++pp){
      int p = t + pp*256;
      if (p < O_*RN){
        int o = p / RN, r = p % RN;
        const float* qrow = q + ((size_t)(b*O_ + o))*E_;
        float acc = 0.f;
        for (int e = 0; e < E_; ++e) acc += qrow[e] * kl[r*513 + e];
        qr[o*20 + r] = acc;
      }
    }
    __syncthreads();
    if (t < O_){
      int o = t;
      float bh = qr[o*20], bl = qr[o*20]; int ih = 0, il = 0;
#pragma unroll
      for (int r = 1; r < RN; ++r){
        float v = qr[o*20 + r];
        if (v > bh){ bh = v; ih = r; }
        if (v < bl){ bl = v; il = r; }
      }
      int rowbase = b*400 + tt*RN;
      int outi = (b*O_ + o)*T_ + tt;
      hi[outi] = rowbase + ih;
      lo[outi] = rowbase + il;
    }
  } else {
    int g = (bid - 560)*4 + (t >> 6);        // region row id 0..7999
    int l = t & 63;
    const float* hrow = c2 + (size_t)g*NW + 1024;
    float acc = 0.f;
    for (int e = l; e < E_; e += 64) acc += tanhf(hrow[e] + b1[e]) * W2[e];
    for (int of = 32; of; of >>= 1) acc += __shfl_down(acc, of, 64);
    if (l == 0) z[g] = 1.f / (1.f + expf(-(acc + b2[0])));
  }
}

// ---------- out = fpre @ Wo + beta*gce (gce recomputed per block) ----------
__global__ __launch_bounds__(256) void k_outg(const float* __restrict__ fpre, const float* __restrict__ Wo,
                                              const float* __restrict__ z, const int* __restrict__ hi,
                                              const int* __restrict__ lo, const int* __restrict__ labels,
                                              float* __restrict__ out){
  int bo = blockIdx.x, t = threadIdx.x;
  __shared__ float rowv[E_];
  __shared__ float vb[B_];
  __shared__ int cb[B_];
  __shared__ float gsh;
  rowv[t] = fpre[(size_t)bo*E_ + t];
  rowv[t + 256] = fpre[(size_t)bo*E_ + t + 256];
  if (t < B_){ vb[t] = 0.f; cb[t] = 0; }
  __syncthreads();
  for (int p = t; p < B_*O_; p += 256){
    int b = p / O_;
    if (labels[p] != 0){
      float acc = 0.f;
      for (int tt = 0; tt < T_; ++tt){
        float shi = z[hi[p*T_ + tt]];
        float slo = z[lo[p*T_ + tt]];
        acc += (1.f - __powf(shi + 1e-7f, 0.7f)) / 0.7f;
        acc += (1.f - __powf(1.f - slo + 1e-7f, 0.7f)) / 0.7f;
      }
      atomicAdd(&vb[b], acc / (float)T_);
      atomicAdd(&cb[b], 1);
    }
  }
  __syncthreads();
  if (t == 0){
    float g = 0.f;
    for (int b = 0; b < B_; ++b) g += vb[b] / fmaxf((float)cb[b], 1.f);
    gsh = 0.5f * (g / (float)B_);
  }
  __syncthreads();
  float g = gsh;
  float a0 = 0.f, a1 = 0.f;
  for (int ep = 0; ep < E_; ++ep){
    float r = rowv[ep];
    a0 += r * Wo[(size_t)ep*E_ + t];
    a1 += r * Wo[(size_t)ep*E_ + t + 256];
  }
  out[(size_t)bo*E_ + t] = a0 + g;
  out[(size_t)bo*E_ + t + 256] = a1 + g;
}

extern "C" void kernel_launch(void* const* d_in, const int* in_sizes, int n_in,
                              void* d_out, int out_size, void* d_ws, size_t ws_size,
                              hipStream_t stream) {
  (void)in_sizes; (void)n_in; (void)out_size; (void)ws_size;
  const float* F    = (const float*)d_in[0];
  const int*   labels = (const int*)d_in[1];
  const float* TMm  = (const float*)d_in[2];
  const float* entW = (const float*)d_in[3];
  const float* entB = (const float*)d_in[4];
  const float* Wq   = (const float*)d_in[5];
  const float* Wk   = (const float*)d_in[6];
  const float* Wv   = (const float*)d_in[7];
  const float* Wo   = (const float*)d_in[8];
  const float* W1   = (const float*)d_in[9];
  const float* b1   = (const float*)d_in[10];
  const float* W2   = (const float*)d_in[11];
  const float* b2   = (const float*)d_in[12];
  float* out = (float*)d_out;

  size_t off = 0;
  char* wsb = (char*)d_ws;
  auto alloc = [&](size_t bytes) -> char* {
    char* p = wsb + off; off += (bytes + 255) & ~(size_t)255; return p;
  };
  unsigned short* A_kv = (unsigned short*)alloc((size_t)MREG * D_ * 2);
  unsigned short* Wall = (unsigned short*)alloc((size_t)NW * D_ * 2);
  float* umax          = (float*)alloc((size_t)TM_ * D_ * 4);
  unsigned short* gbf  = (unsigned short*)alloc((size_t)NSIM * D_ * 2);
  unsigned short* ubf  = (unsigned short*)alloc((size_t)MSIM * D_ * 2);
  float* rmaxr = (float*)alloc((size_t)400 * D_ * 4);
  float* simc  = (float*)alloc((size_t)MSIM * NSIM * 4);
  float* Gc    = (float*)alloc((size_t)NSIM * NW * 4);
  float* C2    = (float*)alloc((size_t)(MREG + 512) * NW * 4);
  float* qbuf  = (float*)alloc((size_t)B_ * O_ * E_ * 4);
  float* fpre  = (float*)alloc((size_t)B_ * O_ * E_ * 4);
  float* rmsum = (float*)alloc(400 * 4);
  float* msum  = (float*)alloc(TM_ * 4);
  int*   hib   = (int*)alloc(6400 * 4);
  int*   lob   = (int*)alloc(6400 * 4);
  float* zbuf  = (float*)alloc(8000 * 4);

  // fused preprocessing: mempool+gbf | region | weight-transpose | q
  k_pre<<<9024, 256, 0, stream>>>(F, TMm, Wk, Wv, W1, Wall, A_kv, rmaxr, rmsum, ubf,
                                  umax, msum, gbf, labels, entW, entB, Wq, qbuf);
  // combined GEMM: mega | G | sim — 512 blocks = 2/CU, inter-block overlap
  k_gemm3<<<512, 512, 0, stream>>>(A_kv, Wall, ubf, gbf, C2, simc, Gc);
  // prune + fp32 rescore + gather G row into C2 mem rows
  k_pick<<<400, 256, 0, stream>>>(simc, rmaxr, rmsum, umax, msum, Gc, C2);
  // fused post: attention | hi/lo | z-MLP
  k_post<<<2560, 256, 0, stream>>>(qbuf, C2, fpre, hib, lob, b1, W2, b2, zbuf);
  // out = fpre @ Wo + beta*gce
  k_outg<<<B_*O_, 256, 0, stream>>>(fpre, Wo, zbuf, hib, lob, labels, out);
}

// Round 11
// 486.647 us; speedup vs baseline: 1.1340x; 1.1340x over previous
//
#include <hip/hip_runtime.h>

#define B_   20
#define T_   20
#define RN   20
#define D_   4096
#define O_   16
#define E_   512
#define H_   8
#define DH   64
#define TM_  1900
#define MREG 8192         // region rows padded to 32*256
#define NW   1536         // Wk|Wv|W1 output channels
#define NSIM 2048         // TM padded to 8*256
#define MSIM 512          // B*T padded to 2*256
#define CAP  256

using f32x4  = __attribute__((ext_vector_type(4))) float;
using bf16x8 = __attribute__((ext_vector_type(8))) __bf16;

__device__ __forceinline__ unsigned short f2bf(float f){
  unsigned u = __float_as_uint(f);
  u += 0x7fffu + ((u >> 16) & 1u);
  return (unsigned short)(u >> 16);
}

__device__ __forceinline__ void st_bf4(unsigned short* dst, float4 v){
  ushort4 o = make_ushort4(f2bf(v.x), f2bf(v.y), f2bf(v.z), f2bf(v.w));
  *(ushort4*)dst = o;
}

__device__ __forceinline__ float bsum256(float v, float* sh){
  int t = threadIdx.x;
  for (int o = 32; o; o >>= 1) v += __shfl_down(v, o, 64);
  __syncthreads();
  if ((t & 63) == 0) sh[t >> 6] = v;
  __syncthreads();
  return sh[0] + sh[1] + sh[2] + sh[3];
}

__device__ __forceinline__ float bmax256(float v, float* sh){
  int t = threadIdx.x;
  for (int o = 32; o; o >>= 1) v = fmaxf(v, __shfl_down(v, o, 64));
  __syncthreads();
  if ((t & 63) == 0) sh[t >> 6] = v;
  __syncthreads();
  return fmaxf(fmaxf(sh[0], sh[1]), fmaxf(sh[2], sh[3]));
}

__device__ __forceinline__ void gld16(const void* g, void* l){
  __builtin_amdgcn_global_load_lds(
      (const __attribute__((address_space(1))) unsigned int*)g,
      (__attribute__((address_space(3))) unsigned int*)l, 16, 0, 0);
}

// ================= fused preprocessing =================
// [0,2048):   temporal-mem max-pool -> umax/msum/gbf (+pads)
// [2048,2560): region pass -> A_kv (row=bt*20+r), rmaxr, rmsum, ubf (+pads)
// [2560,8704): weight transpose+convert -> Wall
// [8704,9024): q = (onehot@entity_W + b) @ Wq
__global__ __launch_bounds__(256) void k_pre(
    const float* __restrict__ F, const float* __restrict__ TMm,
    const float* __restrict__ Wk, const float* __restrict__ Wv, const float* __restrict__ W1,
    unsigned short* __restrict__ Wall,
    unsigned short* __restrict__ A, float* __restrict__ rmaxr, float* __restrict__ rmsum,
    unsigned short* __restrict__ ubf,
    float* __restrict__ umax, float* __restrict__ msum, unsigned short* __restrict__ gbf,
    const int* __restrict__ labels, const float* __restrict__ entW, const float* __restrict__ entB,
    const float* __restrict__ Wq, float* __restrict__ q){
  __shared__ char smem[4352];
  int bid = blockIdx.x, t = threadIdx.x;
  if (bid < 2048){
    int m = bid;
    if (m >= TM_){   // zero gbf pad rows (sim/G B,A pads)
      int4 zz = make_int4(0,0,0,0);
      int4* r2 = (int4*)(gbf + (size_t)m*D_);
      r2[t] = zz; r2[t + 256] = zz;
      return;
    }
    float* sh = (float*)smem;
    const float* base = TMm + (size_t)m*T_*D_;
    float4 mx[4];
#pragma unroll
    for (int i = 0; i < 4; ++i) mx[i] = make_float4(-1e30f,-1e30f,-1e30f,-1e30f);
    float4 va[2][4];
#pragma unroll
    for (int i = 0; i < 4; ++i) va[0][i] = *(const float4*)(base + i*1024 + t*4);
#pragma unroll
    for (int f = 0; f < T_; ++f){
      int c = f & 1;
      if (f + 1 < T_){   // prefetch next frame while reducing current
#pragma unroll
        for (int i = 0; i < 4; ++i)
          va[c^1][i] = *(const float4*)(base + (size_t)(f+1)*D_ + i*1024 + t*4);
      }
#pragma unroll
      for (int i = 0; i < 4; ++i){
        mx[i].x = fmaxf(mx[i].x, va[c][i].x); mx[i].y = fmaxf(mx[i].y, va[c][i].y);
        mx[i].z = fmaxf(mx[i].z, va[c][i].z); mx[i].w = fmaxf(mx[i].w, va[c][i].w);
      }
    }
    float s = 0.f;
#pragma unroll
    for (int i = 0; i < 4; ++i){
      *(float4*)(umax + (size_t)m*D_ + i*1024 + t*4) = mx[i];
      st_bf4(gbf + (size_t)m*D_ + i*1024 + t*4, mx[i]);   // sim-B and G-A operand
      s += mx[i].x*mx[i].x + mx[i].y*mx[i].y + mx[i].z*mx[i].z + mx[i].w*mx[i].w;
    }
    s = bsum256(s, sh);
    if (t == 0) msum[m] = s;
  } else if (bid < 2560){
    int bt = bid - 2048;
    if (bt >= 400){  // zero ubf pad row + two A_kv pad rows
      int4 zz = make_int4(0,0,0,0);
      int4* r1 = (int4*)(ubf + (size_t)bt*D_);
      r1[t] = zz; r1[t + 256] = zz;
      int base = 8000 + (bt - 400)*2;
#pragma unroll
      for (int k = 0; k < 2; ++k){
        if (base + k < MREG){
          int4* r2 = (int4*)(A + (size_t)(base + k)*D_);
          r2[t] = zz; r2[t + 256] = zz;
        }
      }
      return;
    }
    float* sh = (float*)smem;
    const float* fb = F + (size_t)bt*RN*D_;
    unsigned short* ab = A + (size_t)bt*RN*D_;
    float4 mx[4];
#pragma unroll
    for (int i = 0; i < 4; ++i) mx[i] = make_float4(-1e30f,-1e30f,-1e30f,-1e30f);
    float4 vn[4];
#pragma unroll
    for (int i = 0; i < 4; ++i) vn[i] = *(const float4*)(fb + i*1024 + t*4);
    for (int r = 0; r < RN; ++r){
      float4 v[4];
      float s = 0.f;
#pragma unroll
      for (int i = 0; i < 4; ++i){
        v[i] = vn[i];
        s += v[i].x*v[i].x + v[i].y*v[i].y + v[i].z*v[i].z + v[i].w*v[i].w;
      }
      if (r + 1 < RN){   // prefetch next row before the barrier-reduce
#pragma unroll
        for (int i = 0; i < 4; ++i)
          vn[i] = *(const float4*)(fb + (size_t)(r+1)*D_ + i*1024 + t*4);
      }
      s = bsum256(s, sh);
      float ri = 1.f / fmaxf(sqrtf(s), 1e-12f);
#pragma unroll
      for (int i = 0; i < 4; ++i){
        v[i].x *= ri; v[i].y *= ri; v[i].z *= ri; v[i].w *= ri;
        st_bf4(ab + (size_t)r*D_ + i*1024 + t*4, v[i]);
        mx[i].x = fmaxf(mx[i].x, v[i].x); mx[i].y = fmaxf(mx[i].y, v[i].y);
        mx[i].z = fmaxf(mx[i].z, v[i].z); mx[i].w = fmaxf(mx[i].w, v[i].w);
      }
    }
    float s2 = 0.f;
#pragma unroll
    for (int i = 0; i < 4; ++i){
      *(float4*)(rmaxr + (size_t)bt*D_ + i*1024 + t*4) = mx[i];
      s2 += mx[i].x*mx[i].x + mx[i].y*mx[i].y + mx[i].z*mx[i].z + mx[i].w*mx[i].w;
    }
    s2 = bsum256(s2, sh);
    if (t == 0) rmsum[bt] = s2;
    float inv = 1.f / fmaxf(sqrtf(s2), 1e-12f);
#pragma unroll
    for (int i = 0; i < 4; ++i){
      float4 u = mx[i];
      u.x *= inv; u.y *= inv; u.z *= inv; u.w *= inv;
      st_bf4(ubf + (size_t)bt*D_ + i*1024 + t*4, u);
    }
  } else if (bid < 8704){
    int wti = bid - 2560;
    float* tile = (float*)smem;          // [32][33]
    int kb = (wti & 127) * 32, nb = (wti >> 7) * 32;
    const float* src; int nc0;
    if (nb < 512)      { src = Wk; nc0 = nb; }
    else if (nb < 1024){ src = Wv; nc0 = nb - 512; }
    else               { src = W1; nc0 = nb - 1024; }
    int tx = t & 31, ty = t >> 5;
#pragma unroll
    for (int j = 0; j < 4; ++j){
      int k = kb + ty + j*8;
      tile[(ty + j*8)*33 + tx] = src[(size_t)k*E_ + nc0 + tx];
    }
    __syncthreads();
#pragma unroll
    for (int j = 0; j < 4; ++j){
      int n = nb + ty + j*8;
      int k = kb + tx;
      Wall[(size_t)n*D_ + k] = f2bf(tile[tx*33 + ty + j*8]);
    }
  } else {
    int bo = bid - 8704;
    float* qe = (float*)smem;
    int lab = labels[bo];
    float sel = (lab != 0) ? 1.f : 0.f;
    qe[t]       = sel * entW[(size_t)lab*E_ + t]       + entB[t];
    qe[t + 256] = sel * entW[(size_t)lab*E_ + t + 256] + entB[t + 256];
    __syncthreads();
    float a0 = 0.f, a1 = 0.f;
    for (int ep = 0; ep < E_; ++ep){
      float r = qe[ep];
      a0 += r * Wq[(size_t)ep*E_ + t];
      a1 += r * Wq[(size_t)ep*E_ + t + 256];
    }
    q[(size_t)bo*E_ + t] = a0;
    q[(size_t)bo*E_ + t + 256] = a1;
  }
}

// ---------- combined 256x256 bf16 GEMM dispatch: mega | sim | G ----------
// 256 blocks = 1/CU. BK=64, 8 waves, double-buffered prefetch, 1 barrier/K-tile
// (R5/R8 proven body). NEW: panel-sharing XCD swizzle — XCD x (= blockIdx&7,
// round-robin HW mapping) gets mega mt in {x,x+8,x+16,x+24} x all 6 nt, sim
// (mt 0..1, nt=x), G (mt=x, all nt). Co-resident blocks on one XCD share
// A-panels (6-way) and B-panels (4+-way), so tile-stages hit L2 instead of L3.
__global__ __launch_bounds__(512, 1) void k_gemm3(
    const unsigned short* __restrict__ Akv, const unsigned short* __restrict__ Wall,
    const unsigned short* __restrict__ ubf, const unsigned short* __restrict__ gbf,
    float* __restrict__ C2, float* __restrict__ simc, float* __restrict__ Gc){
  __shared__ char lds[131072];   // buf c at c*65536: A[256][64] @ +0, B[256][64] @ +32768
  int x = blockIdx.x & 7, s = blockIdx.x >> 3;   // XCD id, slot on XCD
  const unsigned short *A, *Bw; float* C; int ldc, mt, nt;
  if (s < 24){        A = Akv; Bw = Wall;  C = C2;   ldc = NW;   mt = x + 8*(s/6); nt = s % 6; }
  else if (s < 26){   A = ubf; Bw = gbf;   C = simc; ldc = NSIM; mt = s - 24;      nt = x; }
  else {              A = gbf; Bw = Wall;  C = Gc;   ldc = NW;   mt = x;           nt = s - 26; }
  int tid = threadIdx.x, wid = tid >> 6, l = tid & 63;
  int wr = (wid >> 2) * 128;     // 2 waves in M
  int wc = (wid & 3) * 64;       // 4 waves in N
  int fr = l & 15, fq = l >> 4;
  const char* Ab = (const char*)A + (size_t)mt*256*(size_t)(D_*2);
  const char* Bb = (const char*)Bw + (size_t)nt*256*(size_t)(D_*2);
  f32x4 acc[8][4];
#pragma unroll
  for (int m = 0; m < 8; ++m)
#pragma unroll
    for (int n = 0; n < 4; ++n) acc[m][n] = (f32x4){0.f,0.f,0.f,0.f};

#pragma unroll
  for (int i = 0; i < 4; ++i){   // stage K-tile 0 into buf 0
    int idx = i*512 + tid;
    int row = idx >> 3, u = idx & 7;
    int ul = u ^ (row & 7);
    gld16(Ab + (size_t)row*(D_*2) + (size_t)(ul*16), lds + idx*16);
    gld16(Bb + (size_t)row*(D_*2) + (size_t)(ul*16), lds + 32768 + idx*16);
  }
  __syncthreads();

  int c = 0;
  for (int kt = 0; kt < D_/64; ++kt){
    if (kt < D_/64 - 1){
      int ktoff = (kt + 1) * 128;
      char* dA = lds + (c^1)*65536;
      char* dB = dA + 32768;
#pragma unroll
      for (int i = 0; i < 4; ++i){
        int idx = i*512 + tid;
        int row = idx >> 3, u = idx & 7;
        int ul = u ^ (row & 7);
        gld16(Ab + (size_t)row*(D_*2) + ktoff + ul*16, dA + idx*16);
        gld16(Bb + (size_t)row*(D_*2) + ktoff + ul*16, dB + idx*16);
      }
    }
    const char* LA = lds + c*65536;
    const char* LB = LA + 32768;
    bf16x8 bv[4][2];
#pragma unroll
    for (int n = 0; n < 4; ++n)
#pragma unroll
      for (int kk = 0; kk < 2; ++kk){
        int row = wc + n*16 + fr;
        int u = (kk*4 + fq) ^ (row & 7);
        bv[n][kk] = *(const bf16x8*)(LB + row*128 + u*16);
      }
    __builtin_amdgcn_s_setprio(1);
#pragma unroll
    for (int mp = 0; mp < 4; ++mp){
      bf16x8 av[2][2];
#pragma unroll
      for (int mm = 0; mm < 2; ++mm)
#pragma unroll
        for (int kk = 0; kk < 2; ++kk){
          int row = wr + (mp*2 + mm)*16 + fr;
          int u = (kk*4 + fq) ^ (row & 7);
          av[mm][kk] = *(const bf16x8*)(LA + row*128 + u*16);
        }
#pragma unroll
      for (int mm = 0; mm < 2; ++mm)
#pragma unroll
        for (int n = 0; n < 4; ++n)
#pragma unroll
          for (int kk = 0; kk < 2; ++kk)
            acc[mp*2 + mm][n] = __builtin_amdgcn_mfma_f32_16x16x32_bf16(
                av[mm][kk], bv[n][kk], acc[mp*2 + mm][n], 0, 0, 0);
    }
    __builtin_amdgcn_s_setprio(0);
    __syncthreads();
    c ^= 1;
  }
  size_t crow0 = (size_t)mt*256 + wr, ccol0 = (size_t)nt*256 + wc;
#pragma unroll
  for (int m = 0; m < 8; ++m)
#pragma unroll
    for (int n = 0; n < 4; ++n){
      size_t r0 = crow0 + m*16 + fq*4, c0 = ccol0 + n*16 + fr;
#pragma unroll
      for (int j = 0; j < 4; ++j)
        C[(r0 + j)*(size_t)ldc + c0] = acc[m][n][j];
    }
}

// ---------- prune + fp32 rescore + gather precomputed G row into C2 mem rows ----------
__global__ __launch_bounds__(256) void k_pick(const float* __restrict__ simc,
                                              const float* __restrict__ rmaxr, const float* __restrict__ rmsum,
                                              const float* __restrict__ umax, const float* __restrict__ msum,
                                              const float* __restrict__ Gc, float* __restrict__ C2){
  int bt = blockIdx.x, t = threadIdx.x;
  __shared__ float srow[1920];
  __shared__ float sh[4];
  __shared__ int cnt;
  __shared__ int cl[CAP];
  for (int m = t; m < TM_; m += 256)
    srow[m] = simc[(size_t)bt*NSIM + m] * (1.f / fmaxf(sqrtf(msum[m]), 1e-12f));
  if (t == 0) cnt = 0;
  __syncthreads();
  float mx = -1e30f;
  for (int m = t; m < TM_; m += 256) mx = fmaxf(mx, srow[m]);
  mx = bmax256(mx, sh);
  float thr = mx - 2.5e-4f;
  for (int m = t; m < TM_; m += 256){
    if (srow[m] >= thr){
      int p = atomicAdd(&cnt, 1);
      if (p < CAP) cl[p] = m;
    }
  }
  __syncthreads();
  int cn = cnt < CAP ? cnt : CAP;
  float rinvv = 1.f / fmaxf(sqrtf(rmsum[bt]), 1e-12f);
  const float* a = rmaxr + (size_t)bt*D_;
  float best = -1e30f; int bestm = 0x7fffffff;
  for (int ci = 0; ci < cn; ++ci){
    int m = cl[ci];
    const float* wrow = umax + (size_t)m*D_;
    float p = 0.f;
    for (int i = t*4; i < D_; i += 1024){
      float4 av = *(const float4*)(a + i);
      float4 wv = *(const float4*)(wrow + i);
      p += av.x*wv.x + av.y*wv.y + av.z*wv.z + av.w*wv.w;
    }
    p = bsum256(p, sh);
    float sim = p * rinvv * (1.f / fmaxf(sqrtf(msum[m]), 1e-12f));
    if (sim > best || (sim == best && m < bestm)){ best = sim; bestm = m; }
  }
  // gather precomputed mem-row outputs: C2 row (MREG + bt) = Gc[bestm]
  const float4* src = (const float4*)(Gc + (size_t)bestm*NW);
  float4* dst = (float4*)(C2 + (size_t)(MREG + bt)*NW);
  if (t < 128){ dst[t] = src[t]; dst[t + 128] = src[t + 128]; dst[t + 256] = src[t + 256]; }
}

// ================= fused post-GEMM =================
// [0,160): attention per (b,h) ; [160,560): hi/lo per (b,t) ; [560,2560): z-MLP
// C2 row map: region (b,n<400) -> b*400+n ; mem (b,tt) -> MREG + b*20 + tt
__global__ __launch_bounds__(256) void k_post(const float* __restrict__ q, const float* __restrict__ c2,
                                              float* __restrict__ fpre, int* __restrict__ hi,
                                              int* __restrict__ lo, const float* __restrict__ b1,
                                              const float* __restrict__ W2, const float* __restrict__ b2,
                                              float* __restrict__ z){
  __shared__ char smem[58368];
  int bid = blockIdx.x, t = threadIdx.x;
  if (bid < 160){
    int b = bid >> 3, h = bid & 7;
    int w = t >> 6, l = t & 63;
    float* qhp = (float*)smem;               // [16][65]
    float* kb  = (float*)(smem + 4160);      // [105][65]
    float* sc  = (float*)(smem + 31460);     // [16][420]
    for (int i = t; i < O_*DH; i += 256){
      int o = i >> 6, d = i & 63;
      qhp[o*65 + d] = q[((size_t)(b*O_ + o))*E_ + h*DH + d] * 0.125f;
    }
    __syncthreads();
    for (int c = 0; c < 4; ++c){
      for (int i = t; i < 105*DH; i += 256){
        int j = i >> 6, d = i & 63;
        int n = c*105 + j;
        size_t row = n < 400 ? (size_t)b*400 + n : (size_t)MREG + b*20 + (n - 400);
        kb[j*65 + d] = c2[row*NW + h*DH + d];
      }
      __syncthreads();
      for (int i = t; i < O_*105; i += 256){
        int o = i / 105, j = i % 105;
        float acc = 0.f;
        for (int d = 0; d < DH; ++d) acc += qhp[o*65 + d] * kb[j*65 + d];
        sc[o*420 + c*105 + j] = acc;
      }
      __syncthreads();
    }
    for (int oi = 0; oi < 4; ++oi){
      int o = w + oi*4;
      float mxv = -1e30f;
      for (int n = l; n < 420; n += 64) mxv = fmaxf(mxv, sc[o*420 + n]);
      for (int of = 32; of; of >>= 1) mxv = fmaxf(mxv, __shfl_xor(mxv, of, 64));
      float sum = 0.f;
      for (int n = l; n < 420; n += 64){ float e = expf(sc[o*420 + n] - mxv); sc[o*420 + n] = e; sum += e; }
      for (int of = 32; of; of >>= 1) sum += __shfl_xor(sum, of, 64);
      float inv = 1.f / sum;
      for (int n = l; n < 420; n += 64) sc[o*420 + n] *= inv;
    }
    __syncthreads();
    float acc[4] = {0.f, 0.f, 0.f, 0.f};
    for (int c = 0; c < 4; ++c){
      for (int i = t; i < 105*DH; i += 256){
        int j = i >> 6, d = i & 63;
        int n = c*105 + j;
        size_t row = n < 400 ? (size_t)b*400 + n : (size_t)MREG + b*20 + (n - 400);
        kb[j*65 + d] = c2[row*NW + E_ + h*DH + d];
      }
      __syncthreads();
#pragma unroll
      for (int og = 0; og < 4; ++og){
        int o = og*4 + w;
        float a = 0.f;
        for (int j = 0; j < 105; ++j) a += sc[o*420 + c*105 + j] * kb[j*65 + l];
        acc[og] += a;
      }
      __syncthreads();
    }
#pragma unroll
    for (int og = 0; og < 4; ++og){
      int o = og*4 + w;
      fpre[((size_t)(b*O_ + o))*E_ + h*DH + l] = acc[og];
    }
  } else if (bid < 560){
    int bt = bid - 160;
    int b = bt / T_, tt = bt % T_;
    float* kl = (float*)smem;                // [20][513]
    float* qr = (float*)(smem + 41040);      // [16][20]
    for (int i = t; i < RN*E_; i += 256){
      int r = i >> 9, e = i & 511;
      kl[r*513 + e] = c2[((size_t)b*400 + tt*RN + r)*NW + e];
    }
    __syncthreads();
#pragma unroll
    for (int pp = 0; pp < 2; ++pp){
      int p = t + pp*256;
      if (p < O_*RN){
        int o = p / RN, r = p % RN;
        const float* qrow = q + ((size_t)(b*O_ + o))*E_;
        float acc = 0.f;
        for (int e = 0; e < E_; ++e) acc += qrow[e] * kl[r*513 + e];
        qr[o*20 + r] = acc;
      }
    }
    __syncthreads();
    if (t < O_){
      int o = t;
      float bh = qr[o*20], bl = qr[o*20]; int ih = 0, il = 0;
#pragma unroll
      for (int r = 1; r < RN; ++r){
        float v = qr[o*20 + r];
        if (v > bh){ bh = v; ih = r; }
        if (v < bl){ bl = v; il = r; }
      }
      int rowbase = b*400 + tt*RN;
      int outi = (b*O_ + o)*T_ + tt;
      hi[outi] = rowbase + ih;
      lo[outi] = rowbase + il;
    }
  } else {
    int g = (bid - 560)*4 + (t >> 6);        // region row id 0..7999
    int l = t & 63;
    const float* hrow = c2 + (size_t)g*NW + 1024;
    float acc = 0.f;
    for (int e = l; e < E_; e += 64) acc += tanhf(hrow[e] + b1[e]) * W2[e];
    for (int of = 32; of; of >>= 1) acc += __shfl_down(acc, of, 64);
    if (l == 0) z[g] = 1.f / (1.f + expf(-(acc + b2[0])));
  }
}

// ---------- out = fpre @ Wo + beta*gce (gce recomputed per block) ----------
__global__ __launch_bounds__(256) void k_outg(const float* __restrict__ fpre, const float* __restrict__ Wo,
                                              const float* __restrict__ z, const int* __restrict__ hi,
                                              const int* __restrict__ lo, const int* __restrict__ labels,
                                              float* __restrict__ out){
  int bo = blockIdx.x, t = threadIdx.x;
  __shared__ float rowv[E_];
  __shared__ float vb[B_];
  __shared__ int cb[B_];
  __shared__ float gsh;
  rowv[t] = fpre[(size_t)bo*E_ + t];
  rowv[t + 256] = fpre[(size_t)bo*E_ + t + 256];
  if (t < B_){ vb[t] = 0.f; cb[t] = 0; }
  __syncthreads();
  for (int p = t; p < B_*O_; p += 256){
    int b = p / O_;
    if (labels[p] != 0){
      float acc = 0.f;
      for (int tt = 0; tt < T_; ++tt){
        float shi = z[hi[p*T_ + tt]];
        float slo = z[lo[p*T_ + tt]];
        acc += (1.f - __powf(shi + 1e-7f, 0.7f)) / 0.7f;
        acc += (1.f - __powf(1.f - slo + 1e-7f, 0.7f)) / 0.7f;
      }
      atomicAdd(&vb[b], acc / (float)T_);
      atomicAdd(&cb[b], 1);
    }
  }
  __syncthreads();
  if (t == 0){
    float g = 0.f;
    for (int b = 0; b < B_; ++b) g += vb[b] / fmaxf((float)cb[b], 1.f);
    gsh = 0.5f * (g / (float)B_);
  }
  __syncthreads();
  float g = gsh;
  float a0 = 0.f, a1 = 0.f;
  for (int ep = 0; ep < E_; ++ep){
    float r = rowv[ep];
    a0 += r * Wo[(size_t)ep*E_ + t];
    a1 += r * Wo[(size_t)ep*E_ + t + 256];
  }
  out[(size_t)bo*E_ + t] = a0 + g;
  out[(size_t)bo*E_ + t + 256] = a1 + g;
}

extern "C" void kernel_launch(void* const* d_in, const int* in_sizes, int n_in,
                              void* d_out, int out_size, void* d_ws, size_t ws_size,
                              hipStream_t stream) {
  (void)in_sizes; (void)n_in; (void)out_size; (void)ws_size;
  const float* F    = (const float*)d_in[0];
  const int*   labels = (const int*)d_in[1];
  const float* TMm  = (const float*)d_in[2];
  const float* entW = (const float*)d_in[3];
  const float* entB = (const float*)d_in[4];
  const float* Wq   = (const float*)d_in[5];
  const float* Wk   = (const float*)d_in[6];
  const float* Wv   = (const float*)d_in[7];
  const float* Wo   = (const float*)d_in[8];
  const float* W1   = (const float*)d_in[9];
  const float* b1   = (const float*)d_in[10];
  const float* W2   = (const float*)d_in[11];
  const float* b2   = (const float*)d_in[12];
  float* out = (float*)d_out;

  size_t off = 0;
  char* wsb = (char*)d_ws;
  auto alloc = [&](size_t bytes) -> char* {
    char* p = wsb + off; off += (bytes + 255) & ~(size_t)255; return p;
  };
  unsigned short* A_kv = (unsigned short*)alloc((size_t)MREG * D_ * 2);
  unsigned short* Wall = (unsigned short*)alloc((size_t)NW * D_ * 2);
  float* umax          = (float*)alloc((size_t)TM_ * D_ * 4);
  unsigned short* gbf  = (unsigned short*)alloc((size_t)NSIM * D_ * 2);
  unsigned short* ubf  = (unsigned short*)alloc((size_t)MSIM * D_ * 2);
  float* rmaxr = (float*)alloc((size_t)400 * D_ * 4);
  float* simc  = (float*)alloc((size_t)MSIM * NSIM * 4);
  float* Gc    = (float*)alloc((size_t)NSIM * NW * 4);
  float* C2    = (float*)alloc((size_t)(MREG + 512) * NW * 4);
  float* qbuf  = (float*)alloc((size_t)B_ * O_ * E_ * 4);
  float* fpre  = (float*)alloc((size_t)B_ * O_ * E_ * 4);
  float* rmsum = (float*)alloc(400 * 4);
  float* msum  = (float*)alloc(TM_ * 4);
  int*   hib   = (int*)alloc(6400 * 4);
  int*   lob   = (int*)alloc(6400 * 4);
  float* zbuf  = (float*)alloc(8000 * 4);

  // fused preprocessing: mempool+gbf | region | weight-transpose | q
  k_pre<<<9024, 256, 0, stream>>>(F, TMm, Wk, Wv, W1, Wall, A_kv, rmaxr, rmsum, ubf,
                                  umax, msum, gbf, labels, entW, entB, Wq, qbuf);
  // combined GEMM: mega(region) | sim | G — 256 blocks, panel-sharing XCD swizzle
  k_gemm3<<<256, 512, 0, stream>>>(A_kv, Wall, ubf, gbf, C2, simc, Gc);
  // prune + fp32 rescore + gather G row into C2 mem rows
  k_pick<<<400, 256, 0, stream>>>(simc, rmaxr, rmsum, umax, msum, Gc, C2);
  // fused post: attention | hi/lo | z-MLP
  k_post<<<2560, 256, 0, stream>>>(qbuf, C2, fpre, hib, lob, b1, W2, b2, zbuf);
  // out = fpre @ Wo + beta*gce
  k_outg<<<B_*O_, 256, 0, stream>>>(fpre, Wo, zbuf, hib, lob, labels, out);
}